// Round 10
// baseline (276.237 us; speedup 1.0000x reference)
//
#include <hip/hip_runtime.h>

#define NGEN 8
#define NC 16
#define NM 256

// float-element offsets inside d_ws
#define OFF_SMA_T  ((size_t)0)            // [g][j][l][i] sm_a            8192
#define OFF_SALA   ((size_t)8192)         // [g][j][l][i] sm_a*log(sm_a)  8192
#define OFF_SMA_U  ((size_t)16384)        // [g][c][l][p] sm_a (up)       8192
#define OFF_SMB_T  ((size_t)24576)        // [g][m][i]                    32768
#define OFF_LSMB_T ((size_t)57344)        // [g][m][i] log                32768
#define OFF_SMPI   ((size_t)90112)        // 128
#define OFF_LSMPI  ((size_t)90240)        // 128
#define OFF_R4     ((size_t)112224)       // [g][256][16] ratio at lev4
#define OFF_EPS4   ((size_t)144992)       // [g][256][16] eps at lev4
#define OFF_PT     ((size_t)177760)       // [g][341][16] top prior tree
#define OFF_CNT    ((size_t)221408)       // 8 ints (per-gen block counters)
#define OFF_ST     ((size_t)221424)       // [g][256][2784] persisted subtree state
// ST layout (floats): R7[64][16] | R6[16][16] | R5[4][16] | BIL7[64][16] | BIL6[16][16] | BIL5[4][16] | labs[85 ints] | pad
#define ST_R7   0
#define ST_R6   1024
#define ST_R5   1280
#define ST_BIL7 1344
#define ST_BIL6 2368
#define ST_BIL5 2624
#define ST_LAB  2688
#define ST_SZ   2784

template <int CTRL>
__device__ __forceinline__ float dpp_row_add(float v) {
    int s = __builtin_amdgcn_update_dpp(0, __float_as_int(v), CTRL, 0xf, 0xf, false);
    return v + __int_as_float(s);
}
__device__ __forceinline__ float red16(float v) {
    v = dpp_row_add<0x121>(v);
    v = dpp_row_add<0x122>(v);
    v = dpp_row_add<0x124>(v);
    v = dpp_row_add<0x128>(v);
    return v;
}
__device__ __forceinline__ float rcpf(float x) { return __builtin_amdgcn_rcpf(x); }

__device__ __forceinline__ float dot16(const float* A, const float* row) {
    const float4* r4 = (const float4*)row;
    float s = 0.f;
#pragma unroll
    for (int q = 0; q < 4; ++q) {
        float4 rr = r4[q];
        s += A[4 * q] * rr.x + A[4 * q + 1] * rr.y + A[4 * q + 2] * rr.z + A[4 * q + 3] * rr.w;
    }
    return s;
}
__device__ __forceinline__ void dot16x2(const float* A, const float* B, const float* row,
                                        float& s1, float& s2) {
    const float4* r4 = (const float4*)row;
#pragma unroll
    for (int q = 0; q < 4; ++q) {
        float4 rr = r4[q];
        s1 += A[4 * q] * rr.x + A[4 * q + 1] * rr.y + A[4 * q + 2] * rr.z + A[4 * q + 3] * rr.w;
        s2 += B[4 * q] * rr.x + B[4 * q + 1] * rr.y + B[4 * q + 2] * rr.z + B[4 * q + 3] * rr.w;
    }
}

__device__ __forceinline__ void up_step4(const float (*Rch)[16], float (*BILch)[16],
                                         const float (*Ppar)[16], float (*Rpar)[16],
                                         const float* smb, int lab, int nd, int l, int p,
                                         const float* Aup) {
    int ch = 4 * nd + l;
    float bil = dot16(Aup, Rch[ch]);
    BILch[ch][p] = bil;
    float t0 = bil * __shfl_xor(bil, 16);
    float aux = t0 * __shfl_xor(t0, 32);
    float q0 = aux * smb[(size_t)lab * 16 + p];
    float bi = q0 * Ppar[nd][p];
    float ssum = red16(bi);
    if (l == 0) Rpar[nd][p] = q0 * rcpf(ssum);
}

// ---- init: b-softmax (blocks 0..127, one wave); gen blocks (128..135):
//      a-softmax + pi + zero + FULL TOP PRIOR TREE (341 nodes) -> OFF_PT ----
__global__ __launch_bounds__(256) void k_init(const float* __restrict__ a,
                                              const float* __restrict__ b,
                                              const float* __restrict__ pi,
                                              float* __restrict__ ws, float* __restrict__ out) {
    int bx = blockIdx.x, tid = threadIdx.x;
    __shared__ __align__(16) float sAs[1024];
    __shared__ __align__(16) float P[341][16];
    if (bx < 128) {
        if (tid < 64) {
            int g = bx >> 4, i = bx & 15;
            float v[4];
            float mx = -1e30f;
#pragma unroll
            for (int q = 0; q < 4; ++q) {
                v[q] = b[((size_t)(g * NC + i)) * NM + tid + 64 * q];
                mx = fmaxf(mx, v[q]);
            }
#pragma unroll
            for (int o = 1; o < 64; o <<= 1) mx = fmaxf(mx, __shfl_xor(mx, o));
            float e[4], s = 0.f;
#pragma unroll
            for (int q = 0; q < 4; ++q) { e[q] = expf(v[q] - mx); s += e[q]; }
#pragma unroll
            for (int o = 1; o < 64; o <<= 1) s += __shfl_xor(s, o);
            float ls = logf(s), rs = 1.0f / s;
#pragma unroll
            for (int q = 0; q < 4; ++q) {
                int m = tid + 64 * q;
                ws[OFF_SMB_T + ((size_t)g * NM + m) * NC + i] = e[q] * rs;
                ws[OFF_LSMB_T + ((size_t)g * NM + m) * NC + i] = v[q] - mx - ls;
            }
        }
        return;
    }
    int g = bx - 128;
    if (tid < 64) {
        int j = tid >> 2, l = tid & 3;
        size_t base = ((size_t)(g * NC) * NC + j) * 4 + l;  // a[g][i][j][l]
        float v[16];
        float mx = -1e30f;
#pragma unroll
        for (int i = 0; i < 16; ++i) { v[i] = a[base + (size_t)i * 64]; mx = fmaxf(mx, v[i]); }
        float e[16], s = 0.0f;
#pragma unroll
        for (int i = 0; i < 16; ++i) { e[i] = expf(v[i] - mx); s += e[i]; }
        float ls = logf(s), rs = 1.0f / s;
        size_t tb = ((size_t)(g * NC + j) * 4 + l) * NC;
#pragma unroll
        for (int i = 0; i < 16; ++i) {
            float sm = e[i] * rs;
            float lg = v[i] - mx - ls;
            ws[OFF_SMA_T + tb + i] = sm;
            ws[OFF_SALA + tb + i] = sm * lg;
            ws[OFF_SMA_U + ((size_t)(g * NC + i) * 4 + l) * NC + j] = sm;
            sAs[(j * 4 + l) * 16 + i] = sm;
        }
    } else if (tid == 64) {
        float v[16];
        float mx = -1e30f;
#pragma unroll
        for (int i = 0; i < 16; ++i) { v[i] = pi[g * NC + i]; mx = fmaxf(mx, v[i]); }
        float e[16], s = 0.0f;
#pragma unroll
        for (int i = 0; i < 16; ++i) { e[i] = expf(v[i] - mx); s += e[i]; }
        float ls = logf(s), rs = 1.0f / s;
#pragma unroll
        for (int i = 0; i < 16; ++i) {
            float sm = e[i] * rs;
            ws[OFF_SMPI + g * NC + i] = sm;
            ws[OFF_LSMPI + g * NC + i] = v[i] - mx - ls;
            P[0][i] = sm;
        }
        out[g] = 0.0f;
        ((int*)(ws + OFF_CNT))[g] = 0;
    }
    __syncthreads();
    int i = tid & 15, grp = tid >> 4, pos = grp & 3;
    float Areg[16];
#pragma unroll
    for (int j = 0; j < 16; ++j) Areg[j] = sAs[(j * 4 + pos) * 16 + i];
    if (grp < 4) P[1 + grp][i] = dot16(Areg, P[0]);
    __syncthreads();
    P[5 + grp][i] = dot16(Areg, P[1 + (grp >> 2)]);
    __syncthreads();
#pragma unroll
    for (int k = 0; k < 4; ++k) {
        int nl = grp + 16 * k;
        P[21 + nl][i] = dot16(Areg, P[5 + (nl >> 2)]);
    }
    __syncthreads();
#pragma unroll
    for (int k = 0; k < 16; ++k) {
        int nl = grp + 16 * k;
        P[85 + nl][i] = dot16(Areg, P[21 + (nl >> 2)]);
    }
    __syncthreads();
    float* dst = ws + OFF_PT + (size_t)g * 341 * 16;
    for (int k = tid; k < 341 * 4; k += 256) ((float4*)dst)[k] = ((const float4*)&P[0][0])[k];
}

// ---- subtree up + last-block top epilogue ----
__global__ __launch_bounds__(256) void k_sub_up_top(float* __restrict__ ws,
                                                    const int* __restrict__ t,
                                                    float* __restrict__ out) {
    int s = blockIdx.x, g = blockIdx.y, tid = threadIdx.x;
    int v = 85 + s;
    int i = tid & 15, grp = tid >> 4, pos = grp & 3;
    int lane = tid & 63, wv = tid >> 6;
    int l = lane >> 4, p = lane & 15;
    const float* sAg = ws + OFF_SMA_T + (size_t)g * 1024;
    const float* sLg = ws + OFF_SALA + (size_t)g * 1024;
    const float* Aug = ws + OFF_SMA_U + (size_t)g * 1024;
    const float* smb = ws + OFF_SMB_T + (size_t)g * 4096;
    const float* lsmb = ws + OFF_LSMB_T + (size_t)g * 4096;
    const float* ptg = ws + OFF_PT + (size_t)g * 341 * 16;
    const float* r4g = ws + OFF_R4 + (size_t)g * 4096;
    float* eps4 = ws + OFF_EPS4 + (size_t)g * 4096;
    int* cnt = (int*)(ws + OFF_CNT);

    // LDS union: subtree view (ST+temps, 12.5 KB) / top view (17.7 KB)
    __shared__ __align__(16) float U[4432];
    __shared__ int lastFlag;
    float (*R7)[16]   = (float(*)[16])(U + ST_R7);
    float (*R6)[16]   = (float(*)[16])(U + ST_R6);
    float (*R5)[16]   = (float(*)[16])(U + ST_R5);
    float (*BIL7)[16] = (float(*)[16])(U + ST_BIL7);
    float (*BIL6)[16] = (float(*)[16])(U + ST_BIL6);
    float (*BIL5)[16] = (float(*)[16])(U + ST_BIL5);
    int* labs = (int*)(U + ST_LAB);
    float (*P5)[16] = (float(*)[16])(U + 2784);
    float (*P6)[16] = (float(*)[16])(U + 2848);
    float* P4 = U + 3104;

    if (tid < 64) labs[21 + tid] = t[(64 * v + 21 + tid) * 7];
    else if (tid < 80) labs[5 + (tid - 64)] = t[(16 * v + 5 + (tid - 64)) * 7];
    else if (tid < 84) labs[1 + (tid - 80)] = t[(4 * v + 1 + (tid - 80)) * 7];
    else if (tid == 84) labs[0] = t[v * 7];
    else if (tid >= 96 && tid < 112) P4[tid - 96] = ptg[(size_t)(85 + s) * 16 + (tid - 96)];
    float Areg[16];
#pragma unroll
    for (int j = 0; j < 16; ++j) Areg[j] = sAg[(j * 4 + pos) * 16 + i];
    __syncthreads();

    if (tid < 64) P5[grp][i] = dot16(Areg, P4);
    __syncthreads();
    P6[grp][i] = dot16(Areg, P5[grp >> 2]);
    __syncthreads();
#pragma unroll
    for (int k = 0; k < 4; ++k) {
        int nl = grp + 16 * k;
        float s7 = dot16(Areg, P6[nl >> 2]);
        float smbv = smb[(size_t)labs[21 + nl] * 16 + i];
        float bl = smbv * s7;
        float ssum = red16(bl);
        R7[nl][i] = smbv * rcpf(ssum);
    }
    __syncthreads();
    {
        float Aup[16];
#pragma unroll
        for (int c = 0; c < 16; ++c) Aup[c] = Aug[(c * 4 + l) * 16 + p];
#pragma unroll
        for (int r = 0; r < 4; ++r)
            up_step4(R7, BIL7, P6, R6, smb, labs[5 + (wv + 4 * r)], wv + 4 * r, l, p, Aup);
        __syncthreads();
        up_step4(R6, BIL6, P5, R5, smb, labs[1 + wv], wv, l, p, Aup);
        __syncthreads();
        if (wv == 0) {
            float bil = dot16(Aup, R5[l]);
            BIL5[l][p] = bil;
            float t0 = bil * __shfl_xor(bil, 16);
            float aux = t0 * __shfl_xor(t0, 32);
            float q0 = aux * smb[(size_t)labs[0] * 16 + p];
            float bi = q0 * P4[p];
            float ssum = red16(bi);
            if (l == 0) ws[OFF_R4 + ((size_t)g * 256 + s) * 16 + p] = q0 * rcpf(ssum);
        }
    }
    __syncthreads();
    // persist ST (incl labs bits)
    float* dst = ws + OFF_ST + (size_t)(g * 256 + s) * ST_SZ;
    for (int k = tid; k < ST_SZ / 4; k += 256) ((float4*)dst)[k] = ((const float4*)U)[k];
    __threadfence();
    __syncthreads();
    if (tid == 0) lastFlag = (atomicAdd(&cnt[g], 1) == 255);
    __syncthreads();
    if (!lastFlag) return;
    __threadfence();  // acquire: all blocks' r4 stores now visible

    // ================= TOP EPILOGUE (one block per gen) =================
    float (*Pt)[16]   = (float(*)[16])(U);          // rows 0..84
    float (*Bt)[16]   = (float(*)[16])(U + 1360);   // rows 0..84
    float (*BILt)[16] = (float(*)[16])(U + 2720);   // rows 0..84 (1..84 used)
    int* labt = (int*)(U + 4080);                   // 341 ints
    float* wsumT = U + 4424;

    for (int k = tid; k < 85 * 4; k += 256) ((float4*)&Pt[0][0])[k] = ((const float4*)ptg)[k];
    for (int k = tid; k < 341; k += 256) labt[k] = t[k * 7];
    float AupT[16];
#pragma unroll
    for (int c = 0; c < 16; ++c) AupT[c] = Aug[(c * 4 + l) * 16 + p];
    __syncthreads();
    // up lev3 (64 nodes, 4 waves; children ratio from r4; no BIL store for lev4)
    for (int r = 0; r < 16; ++r) {
        int nd = wv + 4 * r;
        float rv = r4g[(size_t)(4 * nd + l) * 16 + p];
        float bil = 0.f;
#pragma unroll
        for (int c = 0; c < 16; ++c) bil += __shfl(rv, c, 16) * AupT[c];
        float t0 = bil * __shfl_xor(bil, 16);
        float aux = t0 * __shfl_xor(t0, 32);
        float bi = aux * smb[(size_t)labt[21 + nd] * 16 + p] * Pt[21 + nd][p];
        float ssum = red16(bi);
        if (l == 0) Bt[21 + nd][p] = bi * rcpf(ssum);
    }
    __syncthreads();
    for (int r = 0; r < 4; ++r) {  // up lev2 (16 nodes)
        int nd = wv + 4 * r, ch = 21 + 4 * nd + l;
        float rv = Bt[ch][p] * rcpf(Pt[ch][p]);
        float bil = 0.f;
#pragma unroll
        for (int c = 0; c < 16; ++c) bil += __shfl(rv, c, 16) * AupT[c];
        BILt[ch][p] = bil;
        float t0 = bil * __shfl_xor(bil, 16);
        float aux = t0 * __shfl_xor(t0, 32);
        float bi = aux * smb[(size_t)labt[5 + nd] * 16 + p] * Pt[5 + nd][p];
        float ssum = red16(bi);
        if (l == 0) Bt[5 + nd][p] = bi * rcpf(ssum);
    }
    __syncthreads();
    {  // up lev1 (4 nodes, one per wave)
        int nd = wv, ch = 5 + 4 * nd + l;
        float rv = Bt[ch][p] * rcpf(Pt[ch][p]);
        float bil = 0.f;
#pragma unroll
        for (int c = 0; c < 16; ++c) bil += __shfl(rv, c, 16) * AupT[c];
        BILt[ch][p] = bil;
        float t0 = bil * __shfl_xor(bil, 16);
        float aux = t0 * __shfl_xor(t0, 32);
        float bi = aux * smb[(size_t)labt[1 + nd] * 16 + p] * Pt[1 + nd][p];
        float ssum = red16(bi);
        if (l == 0) Bt[1 + nd][p] = bi * rcpf(ssum);
    }
    __syncthreads();
    if (wv == 0) {  // up lev0
        int ch = 1 + l;
        float rv = Bt[ch][p] * rcpf(Pt[ch][p]);
        float bil = 0.f;
#pragma unroll
        for (int c = 0; c < 16; ++c) bil += __shfl(rv, c, 16) * AupT[c];
        BILt[ch][p] = bil;
        float t0 = bil * __shfl_xor(bil, 16);
        float aux = t0 * __shfl_xor(t0, 32);
        float bi = aux * smb[(size_t)labt[0] * 16 + p] * Pt[0][p];
        float ssum = red16(bi);
        if (l == 0) Bt[0][p] = bi * rcpf(ssum);
    }
    __syncthreads();
    float acc = 0.f;
    float sLregT[16];
#pragma unroll
    for (int j = 0; j < 16; ++j) sLregT[j] = sLg[(j * 4 + pos) * 16 + i];
    if (tid < 16)
        acc += Bt[0][i] * (ws[OFF_LSMPI + g * 16 + i] + lsmb[(size_t)labt[0] * 16 + i]);
    if (grp < 4) {  // down lev1
        int row = 1 + grp;
        float w = Bt[0][i] * rcpf(BILt[row][i]);
        BILt[row][i] = w;
        float c0 = Bt[row][i] * rcpf(Pt[row][i]);
        float s1 = 0.f, s2 = 0.f;
        dot16x2(Areg, sLregT, BILt[row], s1, s2);
        float esum = c0 * s1, tot = red16(esum), ev = esum * rcpf(tot);
        Bt[row][i] = ev;
        acc += c0 * s2 + ev * lsmb[(size_t)labt[row] * 16 + i];
    }
    __syncthreads();
    {  // down lev2
        int row = 5 + grp;
        float w = Bt[1 + (grp >> 2)][i] * rcpf(BILt[row][i]);
        BILt[row][i] = w;
        float c0 = Bt[row][i] * rcpf(Pt[row][i]);
        float s1 = 0.f, s2 = 0.f;
        dot16x2(Areg, sLregT, BILt[row], s1, s2);
        float esum = c0 * s1, tot = red16(esum), ev = esum * rcpf(tot);
        Bt[row][i] = ev;
        acc += c0 * s2 + ev * lsmb[(size_t)labt[row] * 16 + i];
    }
    __syncthreads();
    for (int k = 0; k < 4; ++k) {  // down lev3
        int nl = grp + 16 * k, row = 21 + nl;
        float w = Bt[5 + (nl >> 2)][i] * rcpf(BILt[row][i]);
        BILt[row][i] = w;
        float c0 = Bt[row][i] * rcpf(Pt[row][i]);
        float s1 = 0.f, s2 = 0.f;
        dot16x2(Areg, sLregT, BILt[row], s1, s2);
        float esum = c0 * s1, tot = red16(esum), ev = esum * rcpf(tot);
        Bt[row][i] = ev;
        acc += c0 * s2 + ev * lsmb[(size_t)labt[row] * 16 + i];
    }
    __syncthreads();
    {  // down lev4: bil recomputed from r4 + AupD; w staged in BILt[grp]
        float AupD[16];
#pragma unroll
        for (int c = 0; c < 16; ++c) AupD[c] = Aug[(c * 4 + pos) * 16 + i];
        for (int k = 0; k < 16; ++k) {
            int nl = grp + 16 * k;
            float bilv = 0.f;
#pragma unroll
            for (int c = 0; c < 16; ++c) bilv += AupD[c] * r4g[(size_t)nl * 16 + c];
            float w = Bt[21 + (nl >> 2)][i] * rcpf(bilv);
            BILt[grp][i] = w;
            float c0 = r4g[(size_t)nl * 16 + i];
            float s1 = 0.f, s2 = 0.f;
            dot16x2(Areg, sLregT, BILt[grp], s1, s2);
            float esum = c0 * s1, tot = red16(esum), ev = esum * rcpf(tot);
            eps4[(size_t)nl * 16 + i] = ev;
            acc += c0 * s2 + ev * lsmb[(size_t)labt[85 + nl] * 16 + i];
        }
    }
#pragma unroll
    for (int o = 1; o < 64; o <<= 1) acc += __shfl_xor(acc, o);
    if (lane == 0) wsumT[wv] = acc;
    __syncthreads();
    if (tid == 0) atomicAdd(&out[g], wsumT[0] + wsumT[1] + wsumT[2] + wsumT[3]);
}

// ---- subtree down: load persisted state (labs included), down sweep + likelihood ----
__global__ __launch_bounds__(256) void k_sub_down(float* __restrict__ ws, float* __restrict__ out) {
    int s = blockIdx.x, g = blockIdx.y, tid = threadIdx.x;
    int i = tid & 15, grp = tid >> 4, pos = grp & 3;
    const float* sAg = ws + OFF_SMA_T + (size_t)g * 1024;
    const float* sLg = ws + OFF_SALA + (size_t)g * 1024;
    const float* lsmb = ws + OFF_LSMB_T + (size_t)g * 4096;

    __shared__ __align__(16) float ST[ST_SZ];
    float (*R7)[16]   = (float(*)[16])(ST + ST_R7);
    float (*R6)[16]   = (float(*)[16])(ST + ST_R6);
    float (*R5)[16]   = (float(*)[16])(ST + ST_R5);
    float (*BIL7)[16] = (float(*)[16])(ST + ST_BIL7);
    float (*BIL6)[16] = (float(*)[16])(ST + ST_BIL6);
    float (*BIL5)[16] = (float(*)[16])(ST + ST_BIL5);
    const int* labs = (const int*)(ST + ST_LAB);
    __shared__ __align__(16) float E4[16];
    __shared__ float wsum[4];

    const float* src = ws + OFF_ST + (size_t)(g * 256 + s) * ST_SZ;
    for (int k = tid; k < ST_SZ / 4; k += 256) ((float4*)ST)[k] = ((const float4*)src)[k];
    if (tid >= 96 && tid < 112)
        E4[tid - 96] = ws[OFF_EPS4 + ((size_t)g * 256 + s) * 16 + (tid - 96)];

    float Areg[16], sLreg[16];
#pragma unroll
    for (int j = 0; j < 16; ++j) {
        Areg[j] = sAg[(j * 4 + pos) * 16 + i];
        sLreg[j] = sLg[(j * 4 + pos) * 16 + i];
    }
    __syncthreads();

    float acc = 0.f;
    if (tid < 64) {  // down lev5
        float w = E4[i] * rcpf(BIL5[grp][i]);
        BIL5[grp][i] = w;
        float c0 = R5[grp][i];
        float s1 = 0.f, s2 = 0.f;
        dot16x2(Areg, sLreg, BIL5[grp], s1, s2);
        float esum = c0 * s1, tot = red16(esum), ev = esum * rcpf(tot);
        R5[grp][i] = ev;
        acc += c0 * s2 + ev * lsmb[(size_t)labs[1 + grp] * 16 + i];
    }
    __syncthreads();
    {  // down lev6
        float w = R5[grp >> 2][i] * rcpf(BIL6[grp][i]);
        BIL6[grp][i] = w;
        float c0 = R6[grp][i];
        float s1 = 0.f, s2 = 0.f;
        dot16x2(Areg, sLreg, BIL6[grp], s1, s2);
        float esum = c0 * s1, tot = red16(esum), ev = esum * rcpf(tot);
        R6[grp][i] = ev;
        acc += c0 * s2 + ev * lsmb[(size_t)labs[5 + grp] * 16 + i];
    }
    __syncthreads();
#pragma unroll
    for (int k = 0; k < 4; ++k) {  // down lev7
        int nl = grp + 16 * k;
        float w = R6[nl >> 2][i] * rcpf(BIL7[nl][i]);
        BIL7[nl][i] = w;
        float c0 = R7[nl][i];
        float s1 = 0.f, s2 = 0.f;
        dot16x2(Areg, sLreg, BIL7[nl], s1, s2);
        float esum = c0 * s1, tot = red16(esum), ev = esum * rcpf(tot);
        acc += c0 * s2 + ev * lsmb[(size_t)labs[21 + nl] * 16 + i];
    }
#pragma unroll
    for (int o = 1; o < 64; o <<= 1) acc += __shfl_xor(acc, o);
    if ((tid & 63) == 0) wsum[tid >> 6] = acc;
    __syncthreads();
    if (tid == 0) atomicAdd(&out[g], wsum[0] + wsum[1] + wsum[2] + wsum[3]);
}

extern "C" void kernel_launch(void* const* d_in, const int* in_sizes, int n_in,
                              void* d_out, int out_size, void* d_ws, size_t ws_size,
                              hipStream_t stream) {
    const float* a = (const float*)d_in[0];
    const float* b = (const float*)d_in[1];
    const float* pi = (const float*)d_in[2];
    const int* t = (const int*)d_in[3];
    float* out = (float*)d_out;
    float* ws = (float*)d_ws;

    k_init<<<136, 256, 0, stream>>>(a, b, pi, ws, out);
    k_sub_up_top<<<dim3(256, NGEN), 256, 0, stream>>>(ws, t, out);
    k_sub_down<<<dim3(256, NGEN), 256, 0, stream>>>(ws, out);
}

// Round 11
// 65.012 us; speedup vs baseline: 4.2490x; 4.2490x over previous
//
#include <hip/hip_runtime.h>

#define NGEN 8
#define NC 16
#define NM 256

// float-element offsets inside d_ws
#define OFF_SMA_T  ((size_t)0)            // [g][j][l][i] sm_a            8192
#define OFF_SALA   ((size_t)8192)         // [g][j][l][i] sm_a*log(sm_a)  8192
#define OFF_SMA_U  ((size_t)16384)        // [g][c][l][p] sm_a (up)       8192
#define OFF_SMB_T  ((size_t)24576)        // [g][m][i]                    32768
#define OFF_LSMB_T ((size_t)57344)        // [g][m][i] log                32768
#define OFF_SMPI   ((size_t)90112)        // 128
#define OFF_LSMPI  ((size_t)90240)        // 128
#define OFF_R4     ((size_t)112224)       // [g][256][16] ratio at lev4
#define OFF_EPS4   ((size_t)144992)       // [g][256][16] eps at lev4
#define OFF_PT     ((size_t)177760)       // [g][341][16] top prior tree
#define OFF_ST     ((size_t)221424)       // [g][256][2784] persisted subtree state
// ST layout (floats): R7[64][16] | R6[16][16] | R5[4][16] | BIL7[64][16] | BIL6[16][16] | BIL5[4][16] | labs[85 ints] | pad
#define ST_R7   0
#define ST_R6   1024
#define ST_R5   1280
#define ST_BIL7 1344
#define ST_BIL6 2368
#define ST_BIL5 2624
#define ST_LAB  2688
#define ST_SZ   2784

template <int CTRL>
__device__ __forceinline__ float dpp_row_add(float v) {
    int s = __builtin_amdgcn_update_dpp(0, __float_as_int(v), CTRL, 0xf, 0xf, false);
    return v + __int_as_float(s);
}
__device__ __forceinline__ float red16(float v) {
    v = dpp_row_add<0x121>(v);
    v = dpp_row_add<0x122>(v);
    v = dpp_row_add<0x124>(v);
    v = dpp_row_add<0x128>(v);
    return v;
}
__device__ __forceinline__ float rcpf(float x) { return __builtin_amdgcn_rcpf(x); }

__device__ __forceinline__ float dot16(const float* A, const float* row) {
    const float4* r4 = (const float4*)row;
    float s = 0.f;
#pragma unroll
    for (int q = 0; q < 4; ++q) {
        float4 rr = r4[q];
        s += A[4 * q] * rr.x + A[4 * q + 1] * rr.y + A[4 * q + 2] * rr.z + A[4 * q + 3] * rr.w;
    }
    return s;
}
__device__ __forceinline__ void dot16x2(const float* A, const float* B, const float* row,
                                        float& s1, float& s2) {
    const float4* r4 = (const float4*)row;
#pragma unroll
    for (int q = 0; q < 4; ++q) {
        float4 rr = r4[q];
        s1 += A[4 * q] * rr.x + A[4 * q + 1] * rr.y + A[4 * q + 2] * rr.z + A[4 * q + 3] * rr.w;
        s2 += B[4 * q] * rr.x + B[4 * q + 1] * rr.y + B[4 * q + 2] * rr.z + B[4 * q + 3] * rr.w;
    }
}

__device__ __forceinline__ void up_step4(const float (*Rch)[16], float (*BILch)[16],
                                         const float (*Ppar)[16], float (*Rpar)[16],
                                         const float* smb, int lab, int nd, int l, int p,
                                         const float* Aup) {
    int ch = 4 * nd + l;
    float bil = dot16(Aup, Rch[ch]);
    BILch[ch][p] = bil;
    float t0 = bil * __shfl_xor(bil, 16);
    float aux = t0 * __shfl_xor(t0, 32);
    float q0 = aux * smb[(size_t)lab * 16 + p];
    float bi = q0 * Ppar[nd][p];
    float ssum = red16(bi);
    if (l == 0) Rpar[nd][p] = q0 * rcpf(ssum);
}

// ---- init: b-softmax (blocks 0..127, one wave); gen blocks (128..135):
//      a-softmax + pi + zero + FULL TOP PRIOR TREE (341 nodes) -> OFF_PT ----
__global__ __launch_bounds__(256) void k_init(const float* __restrict__ a,
                                              const float* __restrict__ b,
                                              const float* __restrict__ pi,
                                              float* __restrict__ ws, float* __restrict__ out) {
    int bx = blockIdx.x, tid = threadIdx.x;
    __shared__ __align__(16) float sAs[1024];
    __shared__ __align__(16) float P[341][16];
    if (bx < 128) {
        if (tid < 64) {
            int g = bx >> 4, i = bx & 15;
            float v[4];
            float mx = -1e30f;
#pragma unroll
            for (int q = 0; q < 4; ++q) {
                v[q] = b[((size_t)(g * NC + i)) * NM + tid + 64 * q];
                mx = fmaxf(mx, v[q]);
            }
#pragma unroll
            for (int o = 1; o < 64; o <<= 1) mx = fmaxf(mx, __shfl_xor(mx, o));
            float e[4], s = 0.f;
#pragma unroll
            for (int q = 0; q < 4; ++q) { e[q] = expf(v[q] - mx); s += e[q]; }
#pragma unroll
            for (int o = 1; o < 64; o <<= 1) s += __shfl_xor(s, o);
            float ls = logf(s), rs = 1.0f / s;
#pragma unroll
            for (int q = 0; q < 4; ++q) {
                int m = tid + 64 * q;
                ws[OFF_SMB_T + ((size_t)g * NM + m) * NC + i] = e[q] * rs;
                ws[OFF_LSMB_T + ((size_t)g * NM + m) * NC + i] = v[q] - mx - ls;
            }
        }
        return;
    }
    int g = bx - 128;
    if (tid < 64) {
        int j = tid >> 2, l = tid & 3;
        size_t base = ((size_t)(g * NC) * NC + j) * 4 + l;  // a[g][i][j][l]
        float v[16];
        float mx = -1e30f;
#pragma unroll
        for (int i = 0; i < 16; ++i) { v[i] = a[base + (size_t)i * 64]; mx = fmaxf(mx, v[i]); }
        float e[16], s = 0.0f;
#pragma unroll
        for (int i = 0; i < 16; ++i) { e[i] = expf(v[i] - mx); s += e[i]; }
        float ls = logf(s), rs = 1.0f / s;
        size_t tb = ((size_t)(g * NC + j) * 4 + l) * NC;
#pragma unroll
        for (int i = 0; i < 16; ++i) {
            float sm = e[i] * rs;
            float lg = v[i] - mx - ls;
            ws[OFF_SMA_T + tb + i] = sm;
            ws[OFF_SALA + tb + i] = sm * lg;
            ws[OFF_SMA_U + ((size_t)(g * NC + i) * 4 + l) * NC + j] = sm;
            sAs[(j * 4 + l) * 16 + i] = sm;
        }
    } else if (tid == 64) {
        float v[16];
        float mx = -1e30f;
#pragma unroll
        for (int i = 0; i < 16; ++i) { v[i] = pi[g * NC + i]; mx = fmaxf(mx, v[i]); }
        float e[16], s = 0.0f;
#pragma unroll
        for (int i = 0; i < 16; ++i) { e[i] = expf(v[i] - mx); s += e[i]; }
        float ls = logf(s), rs = 1.0f / s;
#pragma unroll
        for (int i = 0; i < 16; ++i) {
            float sm = e[i] * rs;
            ws[OFF_SMPI + g * NC + i] = sm;
            ws[OFF_LSMPI + g * NC + i] = v[i] - mx - ls;
            P[0][i] = sm;
        }
        out[g] = 0.0f;
    }
    __syncthreads();
    int i = tid & 15, grp = tid >> 4, pos = grp & 3;
    float Areg[16];
#pragma unroll
    for (int j = 0; j < 16; ++j) Areg[j] = sAs[(j * 4 + pos) * 16 + i];
    if (grp < 4) P[1 + grp][i] = dot16(Areg, P[0]);
    __syncthreads();
    P[5 + grp][i] = dot16(Areg, P[1 + (grp >> 2)]);
    __syncthreads();
#pragma unroll
    for (int k = 0; k < 4; ++k) {
        int nl = grp + 16 * k;
        P[21 + nl][i] = dot16(Areg, P[5 + (nl >> 2)]);
    }
    __syncthreads();
#pragma unroll
    for (int k = 0; k < 16; ++k) {
        int nl = grp + 16 * k;
        P[85 + nl][i] = dot16(Areg, P[21 + (nl >> 2)]);
    }
    __syncthreads();
    float* dst = ws + OFF_PT + (size_t)g * 341 * 16;
    for (int k = tid; k < 341 * 4; k += 256) ((float4*)dst)[k] = ((const float4*)&P[0][0])[k];
}

// ---- subtree up: leaf + up to lev4; P4 from PT; persists ST (incl labs) + r4 ----
__global__ __launch_bounds__(256) void k_sub_up(float* __restrict__ ws,
                                                const int* __restrict__ t) {
    int s = blockIdx.x, g = blockIdx.y, tid = threadIdx.x;
    int v = 85 + s;
    int i = tid & 15, grp = tid >> 4, pos = grp & 3;
    int lane = tid & 63, wv = tid >> 6;
    int l = lane >> 4, p = lane & 15;
    const float* sAg = ws + OFF_SMA_T + (size_t)g * 1024;
    const float* Aug = ws + OFF_SMA_U + (size_t)g * 1024;
    const float* smb = ws + OFF_SMB_T + (size_t)g * 4096;
    const float* ptg = ws + OFF_PT + (size_t)g * 341 * 16;

    __shared__ __align__(16) float ST[ST_SZ];
    float (*R7)[16]   = (float(*)[16])(ST + ST_R7);
    float (*R6)[16]   = (float(*)[16])(ST + ST_R6);
    float (*R5)[16]   = (float(*)[16])(ST + ST_R5);
    float (*BIL7)[16] = (float(*)[16])(ST + ST_BIL7);
    float (*BIL6)[16] = (float(*)[16])(ST + ST_BIL6);
    float (*BIL5)[16] = (float(*)[16])(ST + ST_BIL5);
    int* labs = (int*)(ST + ST_LAB);
    __shared__ __align__(16) float P5[4][16], P6[16][16];
    __shared__ __align__(16) float P4[16];

    if (tid < 64) labs[21 + tid] = t[(64 * v + 21 + tid) * 7];
    else if (tid < 80) labs[5 + (tid - 64)] = t[(16 * v + 5 + (tid - 64)) * 7];
    else if (tid < 84) labs[1 + (tid - 80)] = t[(4 * v + 1 + (tid - 80)) * 7];
    else if (tid == 84) labs[0] = t[v * 7];
    else if (tid >= 96 && tid < 112) P4[tid - 96] = ptg[(size_t)(85 + s) * 16 + (tid - 96)];
    float Areg[16];
#pragma unroll
    for (int j = 0; j < 16; ++j) Areg[j] = sAg[(j * 4 + pos) * 16 + i];
    __syncthreads();

    if (tid < 64) P5[grp][i] = dot16(Areg, P4);
    __syncthreads();
    P6[grp][i] = dot16(Areg, P5[grp >> 2]);
    __syncthreads();
#pragma unroll
    for (int k = 0; k < 4; ++k) {
        int nl = grp + 16 * k;
        float s7 = dot16(Areg, P6[nl >> 2]);
        float smbv = smb[(size_t)labs[21 + nl] * 16 + i];
        float bl = smbv * s7;
        float ssum = red16(bl);
        R7[nl][i] = smbv * rcpf(ssum);
    }
    __syncthreads();
    float Aup[16];
#pragma unroll
    for (int c = 0; c < 16; ++c) Aup[c] = Aug[(c * 4 + l) * 16 + p];
#pragma unroll
    for (int r = 0; r < 4; ++r)
        up_step4(R7, BIL7, P6, R6, smb, labs[5 + (wv + 4 * r)], wv + 4 * r, l, p, Aup);
    __syncthreads();
    up_step4(R6, BIL6, P5, R5, smb, labs[1 + wv], wv, l, p, Aup);
    __syncthreads();
    if (wv == 0) {
        float bil = dot16(Aup, R5[l]);
        BIL5[l][p] = bil;
        float t0 = bil * __shfl_xor(bil, 16);
        float aux = t0 * __shfl_xor(t0, 32);
        float q0 = aux * smb[(size_t)labs[0] * 16 + p];
        float bi = q0 * P4[p];
        float ssum = red16(bi);
        if (l == 0) ws[OFF_R4 + ((size_t)g * 256 + s) * 16 + p] = q0 * rcpf(ssum);
    }
    __syncthreads();
    float* dst = ws + OFF_ST + (size_t)(g * 256 + s) * ST_SZ;
    for (int k = tid; k < ST_SZ / 4; k += 256) ((float4*)dst)[k] = ((const float4*)ST)[k];
}

// ---- top levels: Pt from PT; up 3..0, root, down 1..4; one block per gen ----
__global__ __launch_bounds__(1024) void k_top(float* __restrict__ ws, const int* __restrict__ t,
                                              float* __restrict__ out) {
    int g = blockIdx.x, tid = threadIdx.x;
    int i = tid & 15, grp = tid >> 4, pos = grp & 3;
    int lane = tid & 63, wv = tid >> 6;  // 16 waves
    int l = lane >> 4, p = lane & 15;
    const float* sAg = ws + OFF_SMA_T + (size_t)g * 1024;
    const float* sLg = ws + OFF_SALA + (size_t)g * 1024;
    const float* Aug = ws + OFF_SMA_U + (size_t)g * 1024;
    const float* smb = ws + OFF_SMB_T + (size_t)g * 4096;
    const float* lsmb = ws + OFF_LSMB_T + (size_t)g * 4096;
    const float* ptg = ws + OFF_PT + (size_t)g * 341 * 16;
    const float* r4g = ws + OFF_R4 + (size_t)g * 4096;
    float* eps4 = ws + OFF_EPS4 + (size_t)g * 4096;

    __shared__ __align__(16) float Pt[85][16], Bt[85][16], BILt[341][16];
    __shared__ int labt[341];
    __shared__ float wsum[16];

    float Areg[16], Aup[16], sLreg[16];
#pragma unroll
    for (int j = 0; j < 16; ++j) {
        Areg[j] = sAg[(j * 4 + pos) * 16 + i];
        sLreg[j] = sLg[(j * 4 + pos) * 16 + i];
    }
#pragma unroll
    for (int c = 0; c < 16; ++c) Aup[c] = Aug[(c * 4 + l) * 16 + p];
    for (int k = tid; k < 85 * 4; k += 1024) ((float4*)&Pt[0][0])[k] = ((const float4*)ptg)[k];
    if (tid < 341) labt[tid] = t[tid * 7];
    __syncthreads();
    // up lev3 (64 nodes; children ratio from global r4)
    for (int r = 0; r < 4; ++r) {
        int nd = wv + 16 * r;
        int chl = 4 * nd + l;
        float rv = r4g[(size_t)chl * 16 + p];
        float bil = 0.f;
#pragma unroll
        for (int c = 0; c < 16; ++c) bil += __shfl(rv, c, 16) * Aup[c];
        BILt[85 + chl][p] = bil;
        float t0 = bil * __shfl_xor(bil, 16);
        float aux = t0 * __shfl_xor(t0, 32);
        float bi = aux * smb[(size_t)labt[21 + nd] * 16 + p] * Pt[21 + nd][p];
        float ssum = red16(bi);
        if (l == 0) Bt[21 + nd][p] = bi * rcpf(ssum);
    }
    __syncthreads();
    {  // up lev2 (16 nodes)
        int nd = wv, ch = 21 + 4 * nd + l;
        float rv = Bt[ch][p] * rcpf(Pt[ch][p]);
        float bil = 0.f;
#pragma unroll
        for (int c = 0; c < 16; ++c) bil += __shfl(rv, c, 16) * Aup[c];
        BILt[ch][p] = bil;
        float t0 = bil * __shfl_xor(bil, 16);
        float aux = t0 * __shfl_xor(t0, 32);
        float bi = aux * smb[(size_t)labt[5 + nd] * 16 + p] * Pt[5 + nd][p];
        float ssum = red16(bi);
        if (l == 0) Bt[5 + nd][p] = bi * rcpf(ssum);
    }
    __syncthreads();
    if (wv < 4) {  // up lev1 (4 nodes)
        int nd = wv, ch = 5 + 4 * nd + l;
        float rv = Bt[ch][p] * rcpf(Pt[ch][p]);
        float bil = 0.f;
#pragma unroll
        for (int c = 0; c < 16; ++c) bil += __shfl(rv, c, 16) * Aup[c];
        BILt[ch][p] = bil;
        float t0 = bil * __shfl_xor(bil, 16);
        float aux = t0 * __shfl_xor(t0, 32);
        float bi = aux * smb[(size_t)labt[1 + nd] * 16 + p] * Pt[1 + nd][p];
        float ssum = red16(bi);
        if (l == 0) Bt[1 + nd][p] = bi * rcpf(ssum);
    }
    __syncthreads();
    if (wv == 0) {  // up lev0 (root)
        int ch = 1 + l;
        float rv = Bt[ch][p] * rcpf(Pt[ch][p]);
        float bil = 0.f;
#pragma unroll
        for (int c = 0; c < 16; ++c) bil += __shfl(rv, c, 16) * Aup[c];
        BILt[ch][p] = bil;
        float t0 = bil * __shfl_xor(bil, 16);
        float aux = t0 * __shfl_xor(t0, 32);
        float bi = aux * smb[(size_t)labt[0] * 16 + p] * Pt[0][p];
        float ssum = red16(bi);
        if (l == 0) Bt[0][p] = bi * rcpf(ssum);
    }
    __syncthreads();
    float acc = 0.f;
    if (tid < 16)
        acc += Bt[0][i] * (ws[OFF_LSMPI + g * 16 + i] + lsmb[(size_t)labt[0] * 16 + i]);
    if (grp < 4) {  // down lev1
        int row = 1 + grp;
        float w = Bt[0][i] * rcpf(BILt[row][i]);
        BILt[row][i] = w;
        float c0 = Bt[row][i] * rcpf(Pt[row][i]);
        float s1 = 0.f, s2 = 0.f;
        dot16x2(Areg, sLreg, BILt[row], s1, s2);
        float esum = c0 * s1, tot = red16(esum), ev = esum * rcpf(tot);
        Bt[row][i] = ev;
        acc += c0 * s2 + ev * lsmb[(size_t)labt[row] * 16 + i];
    }
    __syncthreads();
    if (grp < 16) {  // down lev2
        int row = 5 + grp;
        float w = Bt[1 + (grp >> 2)][i] * rcpf(BILt[row][i]);
        BILt[row][i] = w;
        float c0 = Bt[row][i] * rcpf(Pt[row][i]);
        float s1 = 0.f, s2 = 0.f;
        dot16x2(Areg, sLreg, BILt[row], s1, s2);
        float esum = c0 * s1, tot = red16(esum), ev = esum * rcpf(tot);
        Bt[row][i] = ev;
        acc += c0 * s2 + ev * lsmb[(size_t)labt[row] * 16 + i];
    }
    __syncthreads();
    {  // down lev3 (64 nodes)
        int row = 21 + grp;
        float w = Bt[5 + (grp >> 2)][i] * rcpf(BILt[row][i]);
        BILt[row][i] = w;
        float c0 = Bt[row][i] * rcpf(Pt[row][i]);
        float s1 = 0.f, s2 = 0.f;
        dot16x2(Areg, sLreg, BILt[row], s1, s2);
        float esum = c0 * s1, tot = red16(esum), ev = esum * rcpf(tot);
        Bt[row][i] = ev;
        acc += c0 * s2 + ev * lsmb[(size_t)labt[row] * 16 + i];
    }
    __syncthreads();
    for (int k = 0; k < 4; ++k) {  // down lev4 (256 nodes)
        int nl = grp + 64 * k;
        int row = 85 + nl;
        float w = Bt[21 + (nl >> 2)][i] * rcpf(BILt[row][i]);
        BILt[row][i] = w;
        float c0 = r4g[(size_t)nl * 16 + i];
        float s1 = 0.f, s2 = 0.f;
        dot16x2(Areg, sLreg, BILt[row], s1, s2);
        float esum = c0 * s1, tot = red16(esum), ev = esum * rcpf(tot);
        eps4[(size_t)nl * 16 + i] = ev;
        acc += c0 * s2 + ev * lsmb[(size_t)labt[row] * 16 + i];
    }
#pragma unroll
    for (int o = 1; o < 64; o <<= 1) acc += __shfl_xor(acc, o);
    if ((tid & 63) == 0) wsum[tid >> 6] = acc;
    __syncthreads();
    if (tid == 0) {
        float stot = 0.f;
#pragma unroll
        for (int w2 = 0; w2 < 16; ++w2) stot += wsum[w2];
        atomicAdd(&out[g], stot);
    }
}

// ---- subtree down: load persisted state (labs included), down sweep + likelihood ----
__global__ __launch_bounds__(256) void k_sub_down(float* __restrict__ ws, float* __restrict__ out) {
    int s = blockIdx.x, g = blockIdx.y, tid = threadIdx.x;
    int i = tid & 15, grp = tid >> 4, pos = grp & 3;
    const float* sAg = ws + OFF_SMA_T + (size_t)g * 1024;
    const float* sLg = ws + OFF_SALA + (size_t)g * 1024;
    const float* lsmb = ws + OFF_LSMB_T + (size_t)g * 4096;

    __shared__ __align__(16) float ST[ST_SZ];
    float (*R7)[16]   = (float(*)[16])(ST + ST_R7);
    float (*R6)[16]   = (float(*)[16])(ST + ST_R6);
    float (*R5)[16]   = (float(*)[16])(ST + ST_R5);
    float (*BIL7)[16] = (float(*)[16])(ST + ST_BIL7);
    float (*BIL6)[16] = (float(*)[16])(ST + ST_BIL6);
    float (*BIL5)[16] = (float(*)[16])(ST + ST_BIL5);
    const int* labs = (const int*)(ST + ST_LAB);
    __shared__ __align__(16) float E4[16];
    __shared__ float wsum[4];

    const float* src = ws + OFF_ST + (size_t)(g * 256 + s) * ST_SZ;
    for (int k = tid; k < ST_SZ / 4; k += 256) ((float4*)ST)[k] = ((const float4*)src)[k];
    if (tid >= 96 && tid < 112)
        E4[tid - 96] = ws[OFF_EPS4 + ((size_t)g * 256 + s) * 16 + (tid - 96)];

    float Areg[16], sLreg[16];
#pragma unroll
    for (int j = 0; j < 16; ++j) {
        Areg[j] = sAg[(j * 4 + pos) * 16 + i];
        sLreg[j] = sLg[(j * 4 + pos) * 16 + i];
    }
    __syncthreads();

    float acc = 0.f;
    if (tid < 64) {  // down lev5
        float w = E4[i] * rcpf(BIL5[grp][i]);
        BIL5[grp][i] = w;
        float c0 = R5[grp][i];
        float s1 = 0.f, s2 = 0.f;
        dot16x2(Areg, sLreg, BIL5[grp], s1, s2);
        float esum = c0 * s1, tot = red16(esum), ev = esum * rcpf(tot);
        R5[grp][i] = ev;
        acc += c0 * s2 + ev * lsmb[(size_t)labs[1 + grp] * 16 + i];
    }
    __syncthreads();
    {  // down lev6
        float w = R5[grp >> 2][i] * rcpf(BIL6[grp][i]);
        BIL6[grp][i] = w;
        float c0 = R6[grp][i];
        float s1 = 0.f, s2 = 0.f;
        dot16x2(Areg, sLreg, BIL6[grp], s1, s2);
        float esum = c0 * s1, tot = red16(esum), ev = esum * rcpf(tot);
        R6[grp][i] = ev;
        acc += c0 * s2 + ev * lsmb[(size_t)labs[5 + grp] * 16 + i];
    }
    __syncthreads();
#pragma unroll
    for (int k = 0; k < 4; ++k) {  // down lev7
        int nl = grp + 16 * k;
        float w = R6[nl >> 2][i] * rcpf(BIL7[nl][i]);
        BIL7[nl][i] = w;
        float c0 = R7[nl][i];
        float s1 = 0.f, s2 = 0.f;
        dot16x2(Areg, sLreg, BIL7[nl], s1, s2);
        float esum = c0 * s1, tot = red16(esum), ev = esum * rcpf(tot);
        acc += c0 * s2 + ev * lsmb[(size_t)labs[21 + nl] * 16 + i];
    }
#pragma unroll
    for (int o = 1; o < 64; o <<= 1) acc += __shfl_xor(acc, o);
    if ((tid & 63) == 0) wsum[tid >> 6] = acc;
    __syncthreads();
    if (tid == 0) atomicAdd(&out[g], wsum[0] + wsum[1] + wsum[2] + wsum[3]);
}

extern "C" void kernel_launch(void* const* d_in, const int* in_sizes, int n_in,
                              void* d_out, int out_size, void* d_ws, size_t ws_size,
                              hipStream_t stream) {
    const float* a = (const float*)d_in[0];
    const float* b = (const float*)d_in[1];
    const float* pi = (const float*)d_in[2];
    const int* t = (const int*)d_in[3];
    float* out = (float*)d_out;
    float* ws = (float*)d_ws;

    k_init<<<136, 256, 0, stream>>>(a, b, pi, ws, out);
    k_sub_up<<<dim3(256, NGEN), 256, 0, stream>>>(ws, t);
    k_top<<<NGEN, 1024, 0, stream>>>(ws, t, out);
    k_sub_down<<<dim3(256, NGEN), 256, 0, stream>>>(ws, out);
}

// Round 12
// 63.948 us; speedup vs baseline: 4.3197x; 1.0166x over previous
//
#include <hip/hip_runtime.h>

#define NGEN 8
#define NC 16
#define NM 256

// float-element offsets inside d_ws
#define OFF_SMA_T  ((size_t)0)            // [g][j][l][i] sm_a            8192
#define OFF_SALA   ((size_t)8192)         // [g][j][l][i] sm_a*log(sm_a)  8192
#define OFF_SMA_U  ((size_t)16384)        // [g][c][l][p] sm_a (up)       8192
#define OFF_SMB_T  ((size_t)24576)        // [g][m][i]                    32768
#define OFF_LSMB_T ((size_t)57344)        // [g][m][i] log                32768
#define OFF_SMPI   ((size_t)90112)        // 128
#define OFF_LSMPI  ((size_t)90240)        // 128
#define OFF_R4     ((size_t)112224)       // [g][256][16] ratio at lev4
#define OFF_BIL4   ((size_t)144992)       // [g][256][16] bil of lev4 nodes
#define OFF_PT     ((size_t)177760)       // [g][341][16] top prior tree
#define OFF_EPS3   ((size_t)221408)       // [g][64][16] eps at lev3
#define OFF_ST     ((size_t)229600)       // [g][256][2784] persisted subtree state
// ST layout (floats): R7[64][16] | R6[16][16] | R5[4][16] | BIL7[64][16] | BIL6[16][16] | BIL5[4][16] | labs[85 ints] | pad
#define ST_R7   0
#define ST_R6   1024
#define ST_R5   1280
#define ST_BIL7 1344
#define ST_BIL6 2368
#define ST_BIL5 2624
#define ST_LAB  2688
#define ST_SZ   2784

template <int CTRL>
__device__ __forceinline__ float dpp_row_add(float v) {
    int s = __builtin_amdgcn_update_dpp(0, __float_as_int(v), CTRL, 0xf, 0xf, false);
    return v + __int_as_float(s);
}
__device__ __forceinline__ float red16(float v) {
    v = dpp_row_add<0x121>(v);
    v = dpp_row_add<0x122>(v);
    v = dpp_row_add<0x124>(v);
    v = dpp_row_add<0x128>(v);
    return v;
}
__device__ __forceinline__ float rcpf(float x) { return __builtin_amdgcn_rcpf(x); }

__device__ __forceinline__ float dot16(const float* A, const float* row) {
    const float4* r4 = (const float4*)row;
    float s = 0.f;
#pragma unroll
    for (int q = 0; q < 4; ++q) {
        float4 rr = r4[q];
        s += A[4 * q] * rr.x + A[4 * q + 1] * rr.y + A[4 * q + 2] * rr.z + A[4 * q + 3] * rr.w;
    }
    return s;
}
__device__ __forceinline__ void dot16x2(const float* A, const float* B, const float* row,
                                        float& s1, float& s2) {
    const float4* r4 = (const float4*)row;
#pragma unroll
    for (int q = 0; q < 4; ++q) {
        float4 rr = r4[q];
        s1 += A[4 * q] * rr.x + A[4 * q + 1] * rr.y + A[4 * q + 2] * rr.z + A[4 * q + 3] * rr.w;
        s2 += B[4 * q] * rr.x + B[4 * q + 1] * rr.y + B[4 * q + 2] * rr.z + B[4 * q + 3] * rr.w;
    }
}

__device__ __forceinline__ void up_step4(const float (*Rch)[16], float (*BILch)[16],
                                         const float (*Ppar)[16], float (*Rpar)[16],
                                         const float* smb, int lab, int nd, int l, int p,
                                         const float* Aup) {
    int ch = 4 * nd + l;
    float bil = dot16(Aup, Rch[ch]);
    BILch[ch][p] = bil;
    float t0 = bil * __shfl_xor(bil, 16);
    float aux = t0 * __shfl_xor(t0, 32);
    float q0 = aux * smb[(size_t)lab * 16 + p];
    float bi = q0 * Ppar[nd][p];
    float ssum = red16(bi);
    if (l == 0) Rpar[nd][p] = q0 * rcpf(ssum);
}

// ---- init: b-softmax (blocks 0..127, one wave); gen blocks (128..135):
//      a-softmax + pi + zero + FULL TOP PRIOR TREE (341 nodes) -> OFF_PT ----
__global__ __launch_bounds__(256) void k_init(const float* __restrict__ a,
                                              const float* __restrict__ b,
                                              const float* __restrict__ pi,
                                              float* __restrict__ ws, float* __restrict__ out) {
    int bx = blockIdx.x, tid = threadIdx.x;
    __shared__ __align__(16) float sAs[1024];
    __shared__ __align__(16) float P[341][16];
    if (bx < 128) {
        if (tid < 64) {
            int g = bx >> 4, i = bx & 15;
            float v[4];
            float mx = -1e30f;
#pragma unroll
            for (int q = 0; q < 4; ++q) {
                v[q] = b[((size_t)(g * NC + i)) * NM + tid + 64 * q];
                mx = fmaxf(mx, v[q]);
            }
#pragma unroll
            for (int o = 1; o < 64; o <<= 1) mx = fmaxf(mx, __shfl_xor(mx, o));
            float e[4], s = 0.f;
#pragma unroll
            for (int q = 0; q < 4; ++q) { e[q] = expf(v[q] - mx); s += e[q]; }
#pragma unroll
            for (int o = 1; o < 64; o <<= 1) s += __shfl_xor(s, o);
            float ls = logf(s), rs = 1.0f / s;
#pragma unroll
            for (int q = 0; q < 4; ++q) {
                int m = tid + 64 * q;
                ws[OFF_SMB_T + ((size_t)g * NM + m) * NC + i] = e[q] * rs;
                ws[OFF_LSMB_T + ((size_t)g * NM + m) * NC + i] = v[q] - mx - ls;
            }
        }
        return;
    }
    int g = bx - 128;
    if (tid < 64) {
        int j = tid >> 2, l = tid & 3;
        size_t base = ((size_t)(g * NC) * NC + j) * 4 + l;  // a[g][i][j][l]
        float v[16];
        float mx = -1e30f;
#pragma unroll
        for (int i = 0; i < 16; ++i) { v[i] = a[base + (size_t)i * 64]; mx = fmaxf(mx, v[i]); }
        float e[16], s = 0.0f;
#pragma unroll
        for (int i = 0; i < 16; ++i) { e[i] = expf(v[i] - mx); s += e[i]; }
        float ls = logf(s), rs = 1.0f / s;
        size_t tb = ((size_t)(g * NC + j) * 4 + l) * NC;
#pragma unroll
        for (int i = 0; i < 16; ++i) {
            float sm = e[i] * rs;
            float lg = v[i] - mx - ls;
            ws[OFF_SMA_T + tb + i] = sm;
            ws[OFF_SALA + tb + i] = sm * lg;
            ws[OFF_SMA_U + ((size_t)(g * NC + i) * 4 + l) * NC + j] = sm;
            sAs[(j * 4 + l) * 16 + i] = sm;
        }
    } else if (tid == 64) {
        float v[16];
        float mx = -1e30f;
#pragma unroll
        for (int i = 0; i < 16; ++i) { v[i] = pi[g * NC + i]; mx = fmaxf(mx, v[i]); }
        float e[16], s = 0.0f;
#pragma unroll
        for (int i = 0; i < 16; ++i) { e[i] = expf(v[i] - mx); s += e[i]; }
        float ls = logf(s), rs = 1.0f / s;
#pragma unroll
        for (int i = 0; i < 16; ++i) {
            float sm = e[i] * rs;
            ws[OFF_SMPI + g * NC + i] = sm;
            ws[OFF_LSMPI + g * NC + i] = v[i] - mx - ls;
            P[0][i] = sm;
        }
        out[g] = 0.0f;
    }
    __syncthreads();
    int i = tid & 15, grp = tid >> 4, pos = grp & 3;
    float Areg[16];
#pragma unroll
    for (int j = 0; j < 16; ++j) Areg[j] = sAs[(j * 4 + pos) * 16 + i];
    if (grp < 4) P[1 + grp][i] = dot16(Areg, P[0]);
    __syncthreads();
    P[5 + grp][i] = dot16(Areg, P[1 + (grp >> 2)]);
    __syncthreads();
#pragma unroll
    for (int k = 0; k < 4; ++k) {
        int nl = grp + 16 * k;
        P[21 + nl][i] = dot16(Areg, P[5 + (nl >> 2)]);
    }
    __syncthreads();
#pragma unroll
    for (int k = 0; k < 16; ++k) {
        int nl = grp + 16 * k;
        P[85 + nl][i] = dot16(Areg, P[21 + (nl >> 2)]);
    }
    __syncthreads();
    float* dst = ws + OFF_PT + (size_t)g * 341 * 16;
    for (int k = tid; k < 341 * 4; k += 256) ((float4*)dst)[k] = ((const float4*)&P[0][0])[k];
}

// ---- subtree up: leaf + up to lev4; P4 from PT; persists ST + r4 + bil4 ----
__global__ __launch_bounds__(256) void k_sub_up(float* __restrict__ ws,
                                                const int* __restrict__ t) {
    int s = blockIdx.x, g = blockIdx.y, tid = threadIdx.x;
    int v = 85 + s;
    int i = tid & 15, grp = tid >> 4, pos = grp & 3;
    int lane = tid & 63, wv = tid >> 6;
    int l = lane >> 4, p = lane & 15;
    const float* sAg = ws + OFF_SMA_T + (size_t)g * 1024;
    const float* Aug = ws + OFF_SMA_U + (size_t)g * 1024;
    const float* smb = ws + OFF_SMB_T + (size_t)g * 4096;
    const float* ptg = ws + OFF_PT + (size_t)g * 341 * 16;

    __shared__ __align__(16) float ST[ST_SZ];
    float (*R7)[16]   = (float(*)[16])(ST + ST_R7);
    float (*R6)[16]   = (float(*)[16])(ST + ST_R6);
    float (*R5)[16]   = (float(*)[16])(ST + ST_R5);
    float (*BIL7)[16] = (float(*)[16])(ST + ST_BIL7);
    float (*BIL6)[16] = (float(*)[16])(ST + ST_BIL6);
    float (*BIL5)[16] = (float(*)[16])(ST + ST_BIL5);
    int* labs = (int*)(ST + ST_LAB);
    __shared__ __align__(16) float P5[4][16], P6[16][16];
    __shared__ __align__(16) float P4[16];

    if (tid < 64) labs[21 + tid] = t[(64 * v + 21 + tid) * 7];
    else if (tid < 80) labs[5 + (tid - 64)] = t[(16 * v + 5 + (tid - 64)) * 7];
    else if (tid < 84) labs[1 + (tid - 80)] = t[(4 * v + 1 + (tid - 80)) * 7];
    else if (tid == 84) labs[0] = t[v * 7];
    else if (tid >= 96 && tid < 112) P4[tid - 96] = ptg[(size_t)(85 + s) * 16 + (tid - 96)];
    float Areg[16];
#pragma unroll
    for (int j = 0; j < 16; ++j) Areg[j] = sAg[(j * 4 + pos) * 16 + i];
    __syncthreads();

    if (tid < 64) P5[grp][i] = dot16(Areg, P4);
    __syncthreads();
    P6[grp][i] = dot16(Areg, P5[grp >> 2]);
    __syncthreads();
#pragma unroll
    for (int k = 0; k < 4; ++k) {
        int nl = grp + 16 * k;
        float s7 = dot16(Areg, P6[nl >> 2]);
        float smbv = smb[(size_t)labs[21 + nl] * 16 + i];
        float bl = smbv * s7;
        float ssum = red16(bl);
        R7[nl][i] = smbv * rcpf(ssum);
    }
    __syncthreads();
    float Aup[16];
#pragma unroll
    for (int c = 0; c < 16; ++c) Aup[c] = Aug[(c * 4 + l) * 16 + p];
#pragma unroll
    for (int r = 0; r < 4; ++r)
        up_step4(R7, BIL7, P6, R6, smb, labs[5 + (wv + 4 * r)], wv + 4 * r, l, p, Aup);
    __syncthreads();
    up_step4(R6, BIL6, P5, R5, smb, labs[1 + wv], wv, l, p, Aup);
    __syncthreads();
    if (wv == 0) {
        float bil = dot16(Aup, R5[l]);
        BIL5[l][p] = bil;
        float t0 = bil * __shfl_xor(bil, 16);
        float aux = t0 * __shfl_xor(t0, 32);
        float q0 = aux * smb[(size_t)labs[0] * 16 + p];
        float bi = q0 * P4[p];
        float ssum = red16(bi);
        float r4v = q0 * rcpf(ssum);
        if (l == 0) {
            ws[OFF_R4 + ((size_t)g * 256 + s) * 16 + p] = r4v;
            P4[p] = r4v;  // stage r4 row for the bil4 dot (P4 is dead now)
        }
        // wave-synchronous: l==0 ds_write above is ordered before this ds_read
        if (l == (s & 3)) {
            float bil4 = dot16(Aup, P4);
            ws[OFF_BIL4 + ((size_t)g * 256 + s) * 16 + p] = bil4;
        }
    }
    __syncthreads();
    float* dst = ws + OFF_ST + (size_t)(g * 256 + s) * ST_SZ;
    for (int k = tid; k < ST_SZ / 4; k += 256) ((float4*)dst)[k] = ((const float4*)ST)[k];
}

// ---- top levels: Pt from PT; up 3..0, root, down 1..3 -> eps3; one block per gen ----
__global__ __launch_bounds__(1024) void k_top(float* __restrict__ ws, const int* __restrict__ t,
                                              float* __restrict__ out) {
    int g = blockIdx.x, tid = threadIdx.x;
    int i = tid & 15, grp = tid >> 4, pos = grp & 3;
    int lane = tid & 63, wv = tid >> 6;  // 16 waves
    int l = lane >> 4, p = lane & 15;
    const float* sAg = ws + OFF_SMA_T + (size_t)g * 1024;
    const float* sLg = ws + OFF_SALA + (size_t)g * 1024;
    const float* Aug = ws + OFF_SMA_U + (size_t)g * 1024;
    const float* smb = ws + OFF_SMB_T + (size_t)g * 4096;
    const float* lsmb = ws + OFF_LSMB_T + (size_t)g * 4096;
    const float* ptg = ws + OFF_PT + (size_t)g * 341 * 16;
    const float* r4g = ws + OFF_R4 + (size_t)g * 4096;
    float* eps3 = ws + OFF_EPS3 + (size_t)g * 1024;

    __shared__ __align__(16) float Pt[85][16], Bt[85][16], BILt[85][16];
    __shared__ int labt[85];
    __shared__ float wsum[16];

    float Areg[16], Aup[16], sLreg[16];
#pragma unroll
    for (int j = 0; j < 16; ++j) {
        Areg[j] = sAg[(j * 4 + pos) * 16 + i];
        sLreg[j] = sLg[(j * 4 + pos) * 16 + i];
    }
#pragma unroll
    for (int c = 0; c < 16; ++c) Aup[c] = Aug[(c * 4 + l) * 16 + p];
    for (int k = tid; k < 85 * 4; k += 1024) ((float4*)&Pt[0][0])[k] = ((const float4*)ptg)[k];
    if (tid < 85) labt[tid] = t[tid * 7];
    __syncthreads();
    // up lev3 (64 nodes; children ratio from global r4; bil NOT kept for lev4)
    for (int r = 0; r < 4; ++r) {
        int nd = wv + 16 * r;
        int chl = 4 * nd + l;
        float rv = r4g[(size_t)chl * 16 + p];
        float bil = 0.f;
#pragma unroll
        for (int c = 0; c < 16; ++c) bil += __shfl(rv, c, 16) * Aup[c];
        float t0 = bil * __shfl_xor(bil, 16);
        float aux = t0 * __shfl_xor(t0, 32);
        float bi = aux * smb[(size_t)labt[21 + nd] * 16 + p] * Pt[21 + nd][p];
        float ssum = red16(bi);
        if (l == 0) Bt[21 + nd][p] = bi * rcpf(ssum);
    }
    __syncthreads();
    {  // up lev2 (16 nodes)
        int nd = wv, ch = 21 + 4 * nd + l;
        float rv = Bt[ch][p] * rcpf(Pt[ch][p]);
        float bil = 0.f;
#pragma unroll
        for (int c = 0; c < 16; ++c) bil += __shfl(rv, c, 16) * Aup[c];
        BILt[ch][p] = bil;
        float t0 = bil * __shfl_xor(bil, 16);
        float aux = t0 * __shfl_xor(t0, 32);
        float bi = aux * smb[(size_t)labt[5 + nd] * 16 + p] * Pt[5 + nd][p];
        float ssum = red16(bi);
        if (l == 0) Bt[5 + nd][p] = bi * rcpf(ssum);
    }
    __syncthreads();
    if (wv < 4) {  // up lev1 (4 nodes)
        int nd = wv, ch = 5 + 4 * nd + l;
        float rv = Bt[ch][p] * rcpf(Pt[ch][p]);
        float bil = 0.f;
#pragma unroll
        for (int c = 0; c < 16; ++c) bil += __shfl(rv, c, 16) * Aup[c];
        BILt[ch][p] = bil;
        float t0 = bil * __shfl_xor(bil, 16);
        float aux = t0 * __shfl_xor(t0, 32);
        float bi = aux * smb[(size_t)labt[1 + nd] * 16 + p] * Pt[1 + nd][p];
        float ssum = red16(bi);
        if (l == 0) Bt[1 + nd][p] = bi * rcpf(ssum);
    }
    __syncthreads();
    if (wv == 0) {  // up lev0 (root)
        int ch = 1 + l;
        float rv = Bt[ch][p] * rcpf(Pt[ch][p]);
        float bil = 0.f;
#pragma unroll
        for (int c = 0; c < 16; ++c) bil += __shfl(rv, c, 16) * Aup[c];
        BILt[ch][p] = bil;
        float t0 = bil * __shfl_xor(bil, 16);
        float aux = t0 * __shfl_xor(t0, 32);
        float bi = aux * smb[(size_t)labt[0] * 16 + p] * Pt[0][p];
        float ssum = red16(bi);
        if (l == 0) Bt[0][p] = bi * rcpf(ssum);
    }
    __syncthreads();
    float acc = 0.f;
    if (tid < 16)
        acc += Bt[0][i] * (ws[OFF_LSMPI + g * 16 + i] + lsmb[(size_t)labt[0] * 16 + i]);
    if (grp < 4) {  // down lev1
        int row = 1 + grp;
        float w = Bt[0][i] * rcpf(BILt[row][i]);
        BILt[row][i] = w;
        float c0 = Bt[row][i] * rcpf(Pt[row][i]);
        float s1 = 0.f, s2 = 0.f;
        dot16x2(Areg, sLreg, BILt[row], s1, s2);
        float esum = c0 * s1, tot = red16(esum), ev = esum * rcpf(tot);
        Bt[row][i] = ev;
        acc += c0 * s2 + ev * lsmb[(size_t)labt[row] * 16 + i];
    }
    __syncthreads();
    if (grp < 16) {  // down lev2
        int row = 5 + grp;
        float w = Bt[1 + (grp >> 2)][i] * rcpf(BILt[row][i]);
        BILt[row][i] = w;
        float c0 = Bt[row][i] * rcpf(Pt[row][i]);
        float s1 = 0.f, s2 = 0.f;
        dot16x2(Areg, sLreg, BILt[row], s1, s2);
        float esum = c0 * s1, tot = red16(esum), ev = esum * rcpf(tot);
        Bt[row][i] = ev;
        acc += c0 * s2 + ev * lsmb[(size_t)labt[row] * 16 + i];
    }
    __syncthreads();
    {  // down lev3 (64 nodes) + eps3 store
        int row = 21 + grp;
        float w = Bt[5 + (grp >> 2)][i] * rcpf(BILt[row][i]);
        BILt[row][i] = w;
        float c0 = Bt[row][i] * rcpf(Pt[row][i]);
        float s1 = 0.f, s2 = 0.f;
        dot16x2(Areg, sLreg, BILt[row], s1, s2);
        float esum = c0 * s1, tot = red16(esum), ev = esum * rcpf(tot);
        eps3[(size_t)grp * 16 + i] = ev;
        acc += c0 * s2 + ev * lsmb[(size_t)labt[row] * 16 + i];
    }
#pragma unroll
    for (int o = 1; o < 64; o <<= 1) acc += __shfl_xor(acc, o);
    if ((tid & 63) == 0) wsum[tid >> 6] = acc;
    __syncthreads();
    if (tid == 0) {
        float stot = 0.f;
#pragma unroll
        for (int w2 = 0; w2 < 16; ++w2) stot += wsum[w2];
        atomicAdd(&out[g], stot);
    }
}

// ---- subtree down: lev4 step from eps3/bil4/r4, then lev5-7 + likelihood ----
__global__ __launch_bounds__(256) void k_sub_down(float* __restrict__ ws, float* __restrict__ out) {
    int s = blockIdx.x, g = blockIdx.y, tid = threadIdx.x;
    int i = tid & 15, grp = tid >> 4, pos = grp & 3;
    const float* sAg = ws + OFF_SMA_T + (size_t)g * 1024;
    const float* sLg = ws + OFF_SALA + (size_t)g * 1024;
    const float* lsmb = ws + OFF_LSMB_T + (size_t)g * 4096;

    __shared__ __align__(16) float ST[ST_SZ];
    float (*R7)[16]   = (float(*)[16])(ST + ST_R7);
    float (*R6)[16]   = (float(*)[16])(ST + ST_R6);
    float (*R5)[16]   = (float(*)[16])(ST + ST_R5);
    float (*BIL7)[16] = (float(*)[16])(ST + ST_BIL7);
    float (*BIL6)[16] = (float(*)[16])(ST + ST_BIL6);
    float (*BIL5)[16] = (float(*)[16])(ST + ST_BIL5);
    const int* labs = (const int*)(ST + ST_LAB);
    __shared__ __align__(16) float E3[16], B4r[16], R4r[16], W4[16], E4[16];
    __shared__ float wsum[4];

    const float* src = ws + OFF_ST + (size_t)(g * 256 + s) * ST_SZ;
    for (int k = tid; k < ST_SZ / 4; k += 256) ((float4*)ST)[k] = ((const float4*)src)[k];
    if (tid >= 96 && tid < 112)
        E3[tid - 96] = ws[OFF_EPS3 + ((size_t)g * 64 + (s >> 2)) * 16 + (tid - 96)];
    else if (tid >= 112 && tid < 128)
        B4r[tid - 112] = ws[OFF_BIL4 + ((size_t)g * 256 + s) * 16 + (tid - 112)];
    else if (tid >= 192 && tid < 208)
        R4r[tid - 192] = ws[OFF_R4 + ((size_t)g * 256 + s) * 16 + (tid - 192)];

    float Areg[16], sLreg[16];
#pragma unroll
    for (int j = 0; j < 16; ++j) {
        Areg[j] = sAg[(j * 4 + pos) * 16 + i];
        sLreg[j] = sLg[(j * 4 + pos) * 16 + i];
    }
    __syncthreads();

    float acc = 0.f;
    // down lev4 (the subtree root; 16 threads whose pos == s&3 hold the right A rows)
    if (grp == (s & 3)) {
        float w = E3[i] * rcpf(B4r[i]);
        W4[i] = w;
        float c0 = R4r[i];
        float s1 = 0.f, s2 = 0.f;
        dot16x2(Areg, sLreg, W4, s1, s2);
        float esum = c0 * s1, tot = red16(esum), ev = esum * rcpf(tot);
        E4[i] = ev;
        acc += c0 * s2 + ev * lsmb[(size_t)labs[0] * 16 + i];
    }
    __syncthreads();
    if (tid < 64) {  // down lev5
        float w = E4[i] * rcpf(BIL5[grp][i]);
        BIL5[grp][i] = w;
        float c0 = R5[grp][i];
        float s1 = 0.f, s2 = 0.f;
        dot16x2(Areg, sLreg, BIL5[grp], s1, s2);
        float esum = c0 * s1, tot = red16(esum), ev = esum * rcpf(tot);
        R5[grp][i] = ev;
        acc += c0 * s2 + ev * lsmb[(size_t)labs[1 + grp] * 16 + i];
    }
    __syncthreads();
    {  // down lev6
        float w = R5[grp >> 2][i] * rcpf(BIL6[grp][i]);
        BIL6[grp][i] = w;
        float c0 = R6[grp][i];
        float s1 = 0.f, s2 = 0.f;
        dot16x2(Areg, sLreg, BIL6[grp], s1, s2);
        float esum = c0 * s1, tot = red16(esum), ev = esum * rcpf(tot);
        R6[grp][i] = ev;
        acc += c0 * s2 + ev * lsmb[(size_t)labs[5 + grp] * 16 + i];
    }
    __syncthreads();
#pragma unroll
    for (int k = 0; k < 4; ++k) {  // down lev7
        int nl = grp + 16 * k;
        float w = R6[nl >> 2][i] * rcpf(BIL7[nl][i]);
        BIL7[nl][i] = w;
        float c0 = R7[nl][i];
        float s1 = 0.f, s2 = 0.f;
        dot16x2(Areg, sLreg, BIL7[nl], s1, s2);
        float esum = c0 * s1, tot = red16(esum), ev = esum * rcpf(tot);
        acc += c0 * s2 + ev * lsmb[(size_t)labs[21 + nl] * 16 + i];
    }
#pragma unroll
    for (int o = 1; o < 64; o <<= 1) acc += __shfl_xor(acc, o);
    if ((tid & 63) == 0) wsum[tid >> 6] = acc;
    __syncthreads();
    if (tid == 0) atomicAdd(&out[g], wsum[0] + wsum[1] + wsum[2] + wsum[3]);
}

extern "C" void kernel_launch(void* const* d_in, const int* in_sizes, int n_in,
                              void* d_out, int out_size, void* d_ws, size_t ws_size,
                              hipStream_t stream) {
    const float* a = (const float*)d_in[0];
    const float* b = (const float*)d_in[1];
    const float* pi = (const float*)d_in[2];
    const int* t = (const int*)d_in[3];
    float* out = (float*)d_out;
    float* ws = (float*)d_ws;

    k_init<<<136, 256, 0, stream>>>(a, b, pi, ws, out);
    k_sub_up<<<dim3(256, NGEN), 256, 0, stream>>>(ws, t);
    k_top<<<NGEN, 1024, 0, stream>>>(ws, t, out);
    k_sub_down<<<dim3(256, NGEN), 256, 0, stream>>>(ws, out);
}